// Round 1
// baseline (854.574 us; speedup 1.0000x reference)
//
#include <hip/hip_runtime.h>
#include <math.h>

#define N_NODES 100000
#define N_EDGES 1600000
#define F 128

// ---------------- CSR build ----------------

__global__ __launch_bounds__(256) void hist_kernel(const int* __restrict__ row,
                                                   int* __restrict__ deg) {
    int e = blockIdx.x * 256 + threadIdx.x;
    if (e < N_EDGES) atomicAdd(&deg[row[e]], 1);
}

__global__ __launch_bounds__(256) void scan_blocks_kernel(const int* __restrict__ deg,
                                                          int* __restrict__ incl,
                                                          int* __restrict__ bsums) {
    __shared__ int s[256];
    int tid = threadIdx.x;
    int i = blockIdx.x * 256 + tid;
    int v = (i < N_NODES) ? deg[i] : 0;
    s[tid] = v;
    __syncthreads();
    for (int off = 1; off < 256; off <<= 1) {
        int t = (tid >= off) ? s[tid - off] : 0;
        __syncthreads();
        s[tid] += t;
        __syncthreads();
    }
    if (i < N_NODES) incl[i] = s[tid];
    if (tid == 255) bsums[blockIdx.x] = s[255];
}

__global__ __launch_bounds__(512) void scan_bsums_kernel(int* __restrict__ bsums, int nb) {
    __shared__ int s[512];
    int tid = threadIdx.x;
    int v = (tid < nb) ? bsums[tid] : 0;
    s[tid] = v;
    __syncthreads();
    for (int off = 1; off < 512; off <<= 1) {
        int t = (tid >= off) ? s[tid - off] : 0;
        __syncthreads();
        s[tid] += t;
        __syncthreads();
    }
    if (tid < nb) bsums[tid] = s[tid] - v;  // exclusive
}

__global__ __launch_bounds__(256) void finalize_kernel(const int* __restrict__ incl,
                                                       const int* __restrict__ deg,
                                                       const int* __restrict__ bsums,
                                                       int* __restrict__ row_start,
                                                       int* __restrict__ cursor,
                                                       float* __restrict__ deg_inv) {
    int i = blockIdx.x * 256 + threadIdx.x;
    if (i < N_NODES) {
        int d = deg[i];
        int excl = incl[i] - d + bsums[blockIdx.x];
        row_start[i] = excl;
        cursor[i] = excl;
        deg_inv[i] = (d > 0) ? (1.0f / (float)d) : 0.0f;
    }
    if (blockIdx.x == 0 && threadIdx.x == 0) row_start[N_NODES] = N_EDGES;
}

__global__ __launch_bounds__(256) void fill_kernel(const int* __restrict__ row,
                                                   const int* __restrict__ col,
                                                   int* __restrict__ cursor,
                                                   int* __restrict__ csr_col) {
    int e = blockIdx.x * 256 + threadIdx.x;
    if (e < N_EDGES) {
        int p = atomicAdd(&cursor[row[e]], 1);
        csr_col[p] = col[e];
    }
}

// ---------------- dense GEMM: Y = X @ W^T + b  (M x 128 @ 128 x 128) ----------------
// Block: 256 threads, tile 32 rows x 128 cols, thread tile 4x4.
// W^T staged in LDS with swizzle j' = (j + 4k) & 127: conflict-free writes & b128 reads.
// LDS = 64KB (wsT) + 16KB (xs) = 80KB -> 2 blocks/CU.

__global__ __launch_bounds__(256) void gemm_bias_kernel(const float* __restrict__ X,
                                                        const float* __restrict__ W,
                                                        const float* __restrict__ bias,
                                                        float* __restrict__ Y) {
    __shared__ float wsT[128 * 128];
    __shared__ float xs[32][128];
    const int tid = threadIdx.x;

    // stage W transposed+swizzled: element W[j][k] -> wsT[k*128 + ((j+4k)&127)]
    for (int e = tid; e < 128 * 128; e += 256) {
        int j = e >> 7, k = e & 127;
        wsT[(k << 7) + ((j + (k << 2)) & 127)] = W[e];
    }
    // stage X tile (32 x 128), float4 coalesced
    const int i0 = blockIdx.x << 5;
    for (int v = tid; v < 32 * 32; v += 256) {
        int r = v >> 5, k4 = (v & 31) << 2;
        *(float4*)&xs[r][k4] = *(const float4*)&X[(size_t)(i0 + r) * F + k4];
    }
    __syncthreads();

    const int jc = (tid & 31) << 2;   // column group (4 cols)
    const int r0 = (tid >> 5) << 2;   // row group (4 rows)
    float acc[4][4] = {};
#pragma unroll 4
    for (int k = 0; k < 128; ++k) {
        float4 w = *(const float4*)&wsT[(k << 7) + ((jc + (k << 2)) & 127)];
#pragma unroll
        for (int i = 0; i < 4; ++i) {
            float xv = xs[r0 + i][k];
            acc[i][0] += xv * w.x;
            acc[i][1] += xv * w.y;
            acc[i][2] += xv * w.z;
            acc[i][3] += xv * w.w;
        }
    }
    float4 bv = *(const float4*)&bias[jc];
#pragma unroll
    for (int i = 0; i < 4; ++i) {
        float4 o;
        o.x = acc[i][0] + bv.x;
        o.y = acc[i][1] + bv.y;
        o.z = acc[i][2] + bv.z;
        o.w = acc[i][3] + bv.w;
        *(float4*)&Y[(size_t)(i0 + r0 + i) * F + jc] = o;
    }
}

// ---------------- SpMM (mean aggregation), one wave per node ----------------

template <bool ELU>
__global__ __launch_bounds__(256) void spmm_kernel(const float* __restrict__ H,
                                                   const int* __restrict__ row_start,
                                                   const int* __restrict__ csr_col,
                                                   const float* __restrict__ deg_inv,
                                                   float* __restrict__ out) {
    int node = (blockIdx.x * 256 + threadIdx.x) >> 6;
    int lane = threadIdx.x & 63;
    if (node >= N_NODES) return;
    int s = row_start[node];
    int e = row_start[node + 1];
    float ax = 0.0f, ay = 0.0f;
    for (int p = s; p < e; ++p) {
        int c = csr_col[p];
        float2 v = *(const float2*)&H[(size_t)c * F + (lane << 1)];
        ax += v.x;
        ay += v.y;
    }
    float di = deg_inv[node];
    ax *= di;
    ay *= di;
    if (ELU) {
        ax = (ax > 0.0f) ? ax : expm1f(ax);
        ay = (ay > 0.0f) ? ay : expm1f(ay);
    }
    float2 o = {ax, ay};
    *(float2*)&out[(size_t)node * F + (lane << 1)] = o;
}

// ---------------- launch ----------------

extern "C" void kernel_launch(void* const* d_in, const int* in_sizes, int n_in,
                              void* d_out, int out_size, void* d_ws, size_t ws_size,
                              hipStream_t stream) {
    const float* x  = (const float*)d_in[0];
    const int*   ei = (const int*)d_in[1];
    const float* W1 = (const float*)d_in[2];
    const float* b1 = (const float*)d_in[3];
    const float* W2 = (const float*)d_in[4];
    const float* b2 = (const float*)d_in[5];
    float* out = (float*)d_out;

    const int* row = ei;             // edge_index[0]
    const int* col = ei + N_EDGES;   // edge_index[1]

    // workspace layout
    float* bufA = (float*)d_ws;                       // N*F
    float* bufB = bufA + (size_t)N_NODES * F;         // N*F
    int* deg       = (int*)(bufB + (size_t)N_NODES * F);
    int* incl      = deg + N_NODES;
    int* bsums     = incl + N_NODES;                  // 512
    int* row_start = bsums + 512;                     // N+1 (+pad)
    int* cursor    = row_start + N_NODES + 2;
    int* csr_col   = cursor + N_NODES;
    float* deg_inv = (float*)(csr_col + N_EDGES);

    const int nblk_nodes = (N_NODES + 255) / 256;     // 391
    const int nblk_edges = N_EDGES / 256;             // 6250

    // CSR build
    hipMemsetAsync(deg, 0, N_NODES * sizeof(int), stream);
    hist_kernel<<<nblk_edges, 256, 0, stream>>>(row, deg);
    scan_blocks_kernel<<<nblk_nodes, 256, 0, stream>>>(deg, incl, bsums);
    scan_bsums_kernel<<<1, 512, 0, stream>>>(bsums, nblk_nodes);
    finalize_kernel<<<nblk_nodes, 256, 0, stream>>>(incl, deg, bsums, row_start, cursor, deg_inv);
    fill_kernel<<<nblk_edges, 256, 0, stream>>>(row, col, cursor, csr_col);

    // layer 1
    gemm_bias_kernel<<<N_NODES / 32, 256, 0, stream>>>(x, W1, b1, bufA);
    spmm_kernel<true><<<(N_NODES * 64) / 256, 256, 0, stream>>>(bufA, row_start, csr_col, deg_inv, bufB);

    // layer 2
    gemm_bias_kernel<<<N_NODES / 32, 256, 0, stream>>>(bufB, W2, b2, bufA);
    spmm_kernel<false><<<(N_NODES * 64) / 256, 256, 0, stream>>>(bufA, row_start, csr_col, deg_inv, out);
}

// Round 2
// 705.954 us; speedup vs baseline: 1.2105x; 1.2105x over previous
//
#include <hip/hip_runtime.h>
#include <math.h>

#define N_NODES 100000
#define N_EDGES 1600000
#define F 128

// ---------------- CSR build ----------------

__global__ __launch_bounds__(256) void hist_kernel(const int* __restrict__ row,
                                                   int* __restrict__ deg) {
    int e = blockIdx.x * 256 + threadIdx.x;
    if (e < N_EDGES) atomicAdd(&deg[row[e]], 1);
}

__global__ __launch_bounds__(256) void scan_blocks_kernel(const int* __restrict__ deg,
                                                          int* __restrict__ incl,
                                                          int* __restrict__ bsums) {
    __shared__ int s[256];
    int tid = threadIdx.x;
    int i = blockIdx.x * 256 + tid;
    int v = (i < N_NODES) ? deg[i] : 0;
    s[tid] = v;
    __syncthreads();
    for (int off = 1; off < 256; off <<= 1) {
        int t = (tid >= off) ? s[tid - off] : 0;
        __syncthreads();
        s[tid] += t;
        __syncthreads();
    }
    if (i < N_NODES) incl[i] = s[tid];
    if (tid == 255) bsums[blockIdx.x] = s[255];
}

__global__ __launch_bounds__(512) void scan_bsums_kernel(int* __restrict__ bsums, int nb) {
    __shared__ int s[512];
    int tid = threadIdx.x;
    int v = (tid < nb) ? bsums[tid] : 0;
    s[tid] = v;
    __syncthreads();
    for (int off = 1; off < 512; off <<= 1) {
        int t = (tid >= off) ? s[tid - off] : 0;
        __syncthreads();
        s[tid] += t;
        __syncthreads();
    }
    if (tid < nb) bsums[tid] = s[tid] - v;  // exclusive
}

__global__ __launch_bounds__(256) void finalize_kernel(const int* __restrict__ incl,
                                                       const int* __restrict__ deg,
                                                       const int* __restrict__ bsums,
                                                       int* __restrict__ row_start,
                                                       int* __restrict__ cursor,
                                                       float* __restrict__ deg_inv) {
    int i = blockIdx.x * 256 + threadIdx.x;
    if (i < N_NODES) {
        int d = deg[i];
        int excl = incl[i] - d + bsums[blockIdx.x];
        row_start[i] = excl;
        cursor[i] = excl;
        deg_inv[i] = (d > 0) ? (1.0f / (float)d) : 0.0f;
    }
    if (blockIdx.x == 0 && threadIdx.x == 0) row_start[N_NODES] = N_EDGES;
}

__global__ __launch_bounds__(256) void fill_kernel(const int* __restrict__ row,
                                                   const int* __restrict__ col,
                                                   int* __restrict__ cursor,
                                                   int* __restrict__ csr_col) {
    int e = blockIdx.x * 256 + threadIdx.x;
    if (e < N_EDGES) {
        int p = atomicAdd(&cursor[row[e]], 1);
        csr_col[p] = col[e];
    }
}

// ---------------- dense GEMM: Y = X @ W^T + b  (M x 128 @ 128 x 128) ----------------
// Block: 256 threads, tile 32 rows x 128 cols, thread tile 4x4.
// W^T staged in LDS with rotation swizzle j' = (j+4k)&127: compute reads are
// rotated-contiguous b128 per quarter-wave -> conflict-free.
// k-loop chunked by 4: x reads are b128 broadcasts (free), 8 b128 LDS / 64 FMA
// per lane per chunk -> VALU-bound.

__global__ __launch_bounds__(256) void gemm_bias_kernel(const float* __restrict__ X,
                                                        const float* __restrict__ W,
                                                        const float* __restrict__ bias,
                                                        float* __restrict__ Y) {
    __shared__ float wsT[128 * 128];
    __shared__ float xs[32][128];
    const int tid = threadIdx.x;

    // stage W transposed+swizzled with float4 global loads:
    // W[j][k0..k0+3] -> wsT[(k0+m)*128 + ((j+4*(k0+m))&127)]
    for (int t = tid; t < 128 * 32; t += 256) {
        int j = t >> 5;
        int k0 = (t & 31) << 2;
        float4 w4 = *(const float4*)&W[(j << 7) + k0];
        wsT[((k0 + 0) << 7) + ((j + ((k0 + 0) << 2)) & 127)] = w4.x;
        wsT[((k0 + 1) << 7) + ((j + ((k0 + 1) << 2)) & 127)] = w4.y;
        wsT[((k0 + 2) << 7) + ((j + ((k0 + 2) << 2)) & 127)] = w4.z;
        wsT[((k0 + 3) << 7) + ((j + ((k0 + 3) << 2)) & 127)] = w4.w;
    }
    // stage X tile (32 x 128), float4 coalesced
    const int i0 = blockIdx.x << 5;
    for (int v = tid; v < 32 * 32; v += 256) {
        int r = v >> 5, k4 = (v & 31) << 2;
        *(float4*)&xs[r][k4] = *(const float4*)&X[(size_t)(i0 + r) * F + k4];
    }
    __syncthreads();

    const int jc = (tid & 31) << 2;   // column group (4 cols)
    const int r0 = (tid >> 5) << 2;   // row group (4 rows)
    float acc[4][4] = {};
    for (int k0 = 0; k0 < 128; k0 += 4) {
        float xk[4][4];
#pragma unroll
        for (int i = 0; i < 4; ++i) {
            float4 t = *(const float4*)&xs[r0 + i][k0];
            xk[i][0] = t.x; xk[i][1] = t.y; xk[i][2] = t.z; xk[i][3] = t.w;
        }
#pragma unroll
        for (int m = 0; m < 4; ++m) {
            int k = k0 + m;
            float4 w = *(const float4*)&wsT[(k << 7) + ((jc + (k << 2)) & 127)];
#pragma unroll
            for (int i = 0; i < 4; ++i) {
                acc[i][0] += xk[i][m] * w.x;
                acc[i][1] += xk[i][m] * w.y;
                acc[i][2] += xk[i][m] * w.z;
                acc[i][3] += xk[i][m] * w.w;
            }
        }
    }
    float4 bv = *(const float4*)&bias[jc];
#pragma unroll
    for (int i = 0; i < 4; ++i) {
        float4 o;
        o.x = acc[i][0] + bv.x;
        o.y = acc[i][1] + bv.y;
        o.z = acc[i][2] + bv.z;
        o.w = acc[i][3] + bv.w;
        *(float4*)&Y[(size_t)(i0 + r0 + i) * F + jc] = o;
    }
}

// ---------------- SpMM (mean aggregation) ----------------
// One wave per node. Lanes 0-31 handle even edges, 32-63 odd edges; each lane
// loads float4 (16 B) of the 512 B row. Explicit 2-pair unroll keeps >=4
// dwordx4 gathers in flight per wave. Halves combined via shfl_down(32).

template <bool ELU>
__global__ __launch_bounds__(256) void spmm_kernel(const float* __restrict__ H,
                                                   const int* __restrict__ row_start,
                                                   const int* __restrict__ csr_col,
                                                   const float* __restrict__ deg_inv,
                                                   float* __restrict__ out) {
    const int node = (blockIdx.x * 256 + threadIdx.x) >> 6;
    const int lane = threadIdx.x & 63;
    const int half = lane >> 5;
    const int fo = (lane & 31) << 2;   // feature offset (float index)

    const int s = row_start[node];
    const int e = row_start[node + 1];

    float ax = 0.f, ay = 0.f, az = 0.f, aw = 0.f;
    int p = s + half;
    // main loop: 2 edges per half per iteration (4 gathers in flight per wave)
    while (p + 2 < e) {
        int c0 = csr_col[p];
        int c1 = csr_col[p + 2];
        float4 v0 = *(const float4*)&H[(size_t)c0 * F + fo];
        float4 v1 = *(const float4*)&H[(size_t)c1 * F + fo];
        ax += v0.x + v1.x;
        ay += v0.y + v1.y;
        az += v0.z + v1.z;
        aw += v0.w + v1.w;
        p += 4;
    }
    if (p < e) {
        int c = csr_col[p];
        float4 v = *(const float4*)&H[(size_t)c * F + fo];
        ax += v.x; ay += v.y; az += v.z; aw += v.w;
    }

    // combine the two halves
    ax += __shfl_down(ax, 32);
    ay += __shfl_down(ay, 32);
    az += __shfl_down(az, 32);
    aw += __shfl_down(aw, 32);

    if (half == 0) {
        float di = deg_inv[node];
        ax *= di; ay *= di; az *= di; aw *= di;
        if (ELU) {
            ax = (ax > 0.f) ? ax : expm1f(ax);
            ay = (ay > 0.f) ? ay : expm1f(ay);
            az = (az > 0.f) ? az : expm1f(az);
            aw = (aw > 0.f) ? aw : expm1f(aw);
        }
        float4 o = {ax, ay, az, aw};
        *(float4*)&out[(size_t)node * F + fo] = o;
    }
}

// ---------------- launch ----------------

extern "C" void kernel_launch(void* const* d_in, const int* in_sizes, int n_in,
                              void* d_out, int out_size, void* d_ws, size_t ws_size,
                              hipStream_t stream) {
    const float* x  = (const float*)d_in[0];
    const int*   ei = (const int*)d_in[1];
    const float* W1 = (const float*)d_in[2];
    const float* b1 = (const float*)d_in[3];
    const float* W2 = (const float*)d_in[4];
    const float* b2 = (const float*)d_in[5];
    float* out = (float*)d_out;

    const int* row = ei;             // edge_index[0]
    const int* col = ei + N_EDGES;   // edge_index[1]

    // workspace layout
    float* bufA = (float*)d_ws;                       // N*F
    float* bufB = bufA + (size_t)N_NODES * F;         // N*F
    int* deg       = (int*)(bufB + (size_t)N_NODES * F);
    int* incl      = deg + N_NODES;
    int* bsums     = incl + N_NODES;                  // 512
    int* row_start = bsums + 512;                     // N+1 (+pad)
    int* cursor    = row_start + N_NODES + 2;
    int* csr_col   = cursor + N_NODES;
    float* deg_inv = (float*)(csr_col + N_EDGES);

    const int nblk_nodes = (N_NODES + 255) / 256;     // 391
    const int nblk_edges = N_EDGES / 256;             // 6250

    // CSR build
    hipMemsetAsync(deg, 0, N_NODES * sizeof(int), stream);
    hist_kernel<<<nblk_edges, 256, 0, stream>>>(row, deg);
    scan_blocks_kernel<<<nblk_nodes, 256, 0, stream>>>(deg, incl, bsums);
    scan_bsums_kernel<<<1, 512, 0, stream>>>(bsums, nblk_nodes);
    finalize_kernel<<<nblk_nodes, 256, 0, stream>>>(incl, deg, bsums, row_start, cursor, deg_inv);
    fill_kernel<<<nblk_edges, 256, 0, stream>>>(row, col, cursor, csr_col);

    // layer 1
    gemm_bias_kernel<<<N_NODES / 32, 256, 0, stream>>>(x, W1, b1, bufA);
    spmm_kernel<true><<<(N_NODES * 64) / 256, 256, 0, stream>>>(bufA, row_start, csr_col, deg_inv, bufB);

    // layer 2
    gemm_bias_kernel<<<N_NODES / 32, 256, 0, stream>>>(bufB, W2, b2, bufA);
    spmm_kernel<false><<<(N_NODES * 64) / 256, 256, 0, stream>>>(bufA, row_start, csr_col, deg_inv, out);
}

// Round 3
// 585.029 us; speedup vs baseline: 1.4607x; 1.2067x over previous
//
#include <hip/hip_runtime.h>
#include <math.h>

#define N_NODES 100000
#define N_EDGES 1600000
#define F 128
#define NBUCK 196            // ceil(100000 / 512) coarse buckets of 512 rows
#define EPB 8192             // edges per bucketize block
#define MAXB 10240           // max edges per bucket staged in LDS (avg 8192, +22 sigma)

// ---------------- CSR build: coalesced two-pass bucket sort ----------------
// R2 post-mortem: atomic-fill's scattered 4B stores caused 105 MB of
// partial-line HBM writebacks at ~0.9 TB/s (= the whole 122 us). This build
// writes everything in contiguous runs instead.

__global__ __launch_bounds__(256) void bucket_hist_kernel(const int* __restrict__ row,
                                                          int* __restrict__ bucket_count) {
    __shared__ int lc[NBUCK];
    for (int i = threadIdx.x; i < NBUCK; i += 256) lc[i] = 0;
    __syncthreads();
    const int stride = gridDim.x * 256;
    for (int e = blockIdx.x * 256 + threadIdx.x; e < N_EDGES; e += stride)
        atomicAdd(&lc[row[e] >> 9], 1);
    __syncthreads();
    for (int i = threadIdx.x; i < NBUCK; i += 256)
        if (lc[i]) atomicAdd(&bucket_count[i], lc[i]);
}

__global__ __launch_bounds__(256) void bucket_scan_kernel(const int* __restrict__ bucket_count,
                                                          int* __restrict__ bucket_base,
                                                          int* __restrict__ bucket_cursor) {
    __shared__ int s[256];
    const int tid = threadIdx.x;
    int v = (tid < NBUCK) ? bucket_count[tid] : 0;
    s[tid] = v;
    __syncthreads();
    for (int off = 1; off < 256; off <<= 1) {
        int t = (tid >= off) ? s[tid - off] : 0;
        __syncthreads();
        s[tid] += t;
        __syncthreads();
    }
    if (tid < NBUCK) {
        int ex = s[tid] - v;
        bucket_base[tid] = ex;
        bucket_cursor[tid] = ex;
    }
    if (tid == NBUCK - 1) bucket_base[NBUCK] = s[tid];  // == N_EDGES
}

// Per block: count 8192 edges into 196 LDS bins, scan, reserve global runs
// (196 atomics), stage reordered pairs in LDS, write out grouped-by-bucket ->
// contiguous runs of ~42 edges (336 B) per bucket per block.
__global__ __launch_bounds__(256) void bucketize_kernel(const int* __restrict__ row,
                                                        const int* __restrict__ col,
                                                        int* __restrict__ bucket_cursor,
                                                        int2* __restrict__ pairs) {
    __shared__ int2 stage[EPB];
    __shared__ int tgt[EPB];
    __shared__ int lcnt[NBUCK], lcnt2[NBUCK], loff[NBUCK], gbase[NBUCK];
    __shared__ int s[256];
    const int tid = threadIdx.x;
    const int base = blockIdx.x * EPB;

    for (int i = tid; i < NBUCK; i += 256) { lcnt[i] = 0; lcnt2[i] = 0; }
    __syncthreads();
    // round 1: count
    for (int i = 0; i < 32; ++i) {
        int e = base + i * 256 + tid;
        if (e < N_EDGES) atomicAdd(&lcnt[row[e] >> 9], 1);
    }
    __syncthreads();
    // exclusive scan of lcnt -> loff
    {
        int v = (tid < NBUCK) ? lcnt[tid] : 0;
        s[tid] = v;
        __syncthreads();
        for (int off = 1; off < 256; off <<= 1) {
            int t = (tid >= off) ? s[tid - off] : 0;
            __syncthreads();
            s[tid] += t;
            __syncthreads();
        }
        if (tid < NBUCK) loff[tid] = s[tid] - v;
    }
    // reserve global runs
    if (tid < NBUCK) {
        int c = lcnt[tid];
        gbase[tid] = c ? atomicAdd(&bucket_cursor[tid], c) : 0;
    }
    __syncthreads();
    // round 2: stage reordered
    for (int i = 0; i < 32; ++i) {
        int e = base + i * 256 + tid;
        if (e < N_EDGES) {
            int r = row[e], c = col[e];
            int b = r >> 9;
            int rk = atomicAdd(&lcnt2[b], 1);
            int q = loff[b] + rk;
            stage[q] = make_int2(r, c);
            tgt[q] = gbase[b] + rk;
        }
    }
    __syncthreads();
    // coalesced write-out (consecutive q -> consecutive tgt within runs)
    const int cnt = min(N_EDGES - base, EPB);
    for (int q = tid; q < cnt; q += 256) pairs[tgt[q]] = stage[q];
}

// One block per bucket: exact per-row CSR within the bucket's 512 rows.
// Produces row_start, deg_inv, and fully-coalesced csr_col.
__global__ __launch_bounds__(512) void csr_finalize_kernel(const int2* __restrict__ pairs,
                                                           const int* __restrict__ bucket_base,
                                                           int* __restrict__ csr_col,
                                                           int* __restrict__ row_start,
                                                           float* __restrict__ deg_inv) {
    __shared__ int rcnt[512], rcnt2[512], ssc[512], roff[512];
    __shared__ int colstage[MAXB];
    const int tid = threadIdx.x;
    const int b = blockIdx.x;
    const int s0 = bucket_base[b], e0 = bucket_base[b + 1];

    rcnt[tid] = 0;
    rcnt2[tid] = 0;
    __syncthreads();
    for (int q = s0 + tid; q < e0; q += 512) atomicAdd(&rcnt[pairs[q].x & 511], 1);
    __syncthreads();
    const int d = rcnt[tid];
    ssc[tid] = d;
    __syncthreads();
    for (int off = 1; off < 512; off <<= 1) {
        int t = (tid >= off) ? ssc[tid - off] : 0;
        __syncthreads();
        ssc[tid] += t;
        __syncthreads();
    }
    const int excl = ssc[tid] - d;
    roff[tid] = excl;
    const int grow = (b << 9) + tid;
    if (grow < N_NODES) {
        row_start[grow] = s0 + excl;
        deg_inv[grow] = d ? 1.0f / (float)d : 0.0f;
    } else if (grow == N_NODES) {
        row_start[N_NODES] = s0 + excl;  // == N_EDGES (only bucket 195 hits this)
    }
    __syncthreads();
    for (int q = s0 + tid; q < e0; q += 512) {
        int2 pc = pairs[q];
        int lr = pc.x & 511;
        int rk = atomicAdd(&rcnt2[lr], 1);
        int idx = roff[lr] + rk;
        if (idx < MAXB) colstage[idx] = pc.y;
        else csr_col[s0 + idx] = pc.y;  // statistically-never fallback
    }
    __syncthreads();
    const int cap = min(e0 - s0, MAXB);
    for (int q = tid; q < cap; q += 512) csr_col[s0 + q] = colstage[q];
}

// ---------------- dense GEMM: Y = X @ W^T + b  (M x 128 @ 128 x 128) ----------------

__global__ __launch_bounds__(256) void gemm_bias_kernel(const float* __restrict__ X,
                                                        const float* __restrict__ W,
                                                        const float* __restrict__ bias,
                                                        float* __restrict__ Y) {
    __shared__ float wsT[128 * 128];
    __shared__ float xs[32][128];
    const int tid = threadIdx.x;

    for (int t = tid; t < 128 * 32; t += 256) {
        int j = t >> 5;
        int k0 = (t & 31) << 2;
        float4 w4 = *(const float4*)&W[(j << 7) + k0];
        wsT[((k0 + 0) << 7) + ((j + ((k0 + 0) << 2)) & 127)] = w4.x;
        wsT[((k0 + 1) << 7) + ((j + ((k0 + 1) << 2)) & 127)] = w4.y;
        wsT[((k0 + 2) << 7) + ((j + ((k0 + 2) << 2)) & 127)] = w4.z;
        wsT[((k0 + 3) << 7) + ((j + ((k0 + 3) << 2)) & 127)] = w4.w;
    }
    const int i0 = blockIdx.x << 5;
    for (int v = tid; v < 32 * 32; v += 256) {
        int r = v >> 5, k4 = (v & 31) << 2;
        *(float4*)&xs[r][k4] = *(const float4*)&X[(size_t)(i0 + r) * F + k4];
    }
    __syncthreads();

    const int jc = (tid & 31) << 2;
    const int r0 = (tid >> 5) << 2;
    float acc[4][4] = {};
    for (int k0 = 0; k0 < 128; k0 += 4) {
        float xk[4][4];
#pragma unroll
        for (int i = 0; i < 4; ++i) {
            float4 t = *(const float4*)&xs[r0 + i][k0];
            xk[i][0] = t.x; xk[i][1] = t.y; xk[i][2] = t.z; xk[i][3] = t.w;
        }
#pragma unroll
        for (int m = 0; m < 4; ++m) {
            int k = k0 + m;
            float4 w = *(const float4*)&wsT[(k << 7) + ((jc + (k << 2)) & 127)];
#pragma unroll
            for (int i = 0; i < 4; ++i) {
                acc[i][0] += xk[i][m] * w.x;
                acc[i][1] += xk[i][m] * w.y;
                acc[i][2] += xk[i][m] * w.z;
                acc[i][3] += xk[i][m] * w.w;
            }
        }
    }
    float4 bv = *(const float4*)&bias[jc];
#pragma unroll
    for (int i = 0; i < 4; ++i) {
        float4 o;
        o.x = acc[i][0] + bv.x;
        o.y = acc[i][1] + bv.y;
        o.z = acc[i][2] + bv.z;
        o.w = acc[i][3] + bv.w;
        *(float4*)&Y[(size_t)(i0 + r0 + i) * F + jc] = o;
    }
}

// ---------------- SpMM (mean aggregation) ----------------

template <bool ELU>
__global__ __launch_bounds__(256) void spmm_kernel(const float* __restrict__ H,
                                                   const int* __restrict__ row_start,
                                                   const int* __restrict__ csr_col,
                                                   const float* __restrict__ deg_inv,
                                                   float* __restrict__ out) {
    const int node = (blockIdx.x * 256 + threadIdx.x) >> 6;
    const int lane = threadIdx.x & 63;
    const int half = lane >> 5;
    const int fo = (lane & 31) << 2;

    const int s = row_start[node];
    const int e = row_start[node + 1];

    float ax = 0.f, ay = 0.f, az = 0.f, aw = 0.f;
    int p = s + half;
    while (p + 2 < e) {
        int c0 = csr_col[p];
        int c1 = csr_col[p + 2];
        float4 v0 = *(const float4*)&H[(size_t)c0 * F + fo];
        float4 v1 = *(const float4*)&H[(size_t)c1 * F + fo];
        ax += v0.x + v1.x;
        ay += v0.y + v1.y;
        az += v0.z + v1.z;
        aw += v0.w + v1.w;
        p += 4;
    }
    if (p < e) {
        int c = csr_col[p];
        float4 v = *(const float4*)&H[(size_t)c * F + fo];
        ax += v.x; ay += v.y; az += v.z; aw += v.w;
    }

    ax += __shfl_down(ax, 32);
    ay += __shfl_down(ay, 32);
    az += __shfl_down(az, 32);
    aw += __shfl_down(aw, 32);

    if (half == 0) {
        float di = deg_inv[node];
        ax *= di; ay *= di; az *= di; aw *= di;
        if (ELU) {
            ax = (ax > 0.f) ? ax : expm1f(ax);
            ay = (ay > 0.f) ? ay : expm1f(ay);
            az = (az > 0.f) ? az : expm1f(az);
            aw = (aw > 0.f) ? aw : expm1f(aw);
        }
        float4 o = {ax, ay, az, aw};
        *(float4*)&out[(size_t)node * F + fo] = o;
    }
}

// ---------------- launch ----------------

extern "C" void kernel_launch(void* const* d_in, const int* in_sizes, int n_in,
                              void* d_out, int out_size, void* d_ws, size_t ws_size,
                              hipStream_t stream) {
    const float* x  = (const float*)d_in[0];
    const int*   ei = (const int*)d_in[1];
    const float* W1 = (const float*)d_in[2];
    const float* b1 = (const float*)d_in[3];
    const float* W2 = (const float*)d_in[4];
    const float* b2 = (const float*)d_in[5];
    float* out = (float*)d_out;

    const int* row = ei;
    const int* col = ei + N_EDGES;

    // workspace layout
    float* bufA = (float*)d_ws;                            // N*F
    float* bufB = bufA + (size_t)N_NODES * F;              // N*F
    int* csr_col = (int*)(bufB + (size_t)N_NODES * F);     // N_EDGES
    int* row_start = csr_col + N_EDGES;                    // N_NODES+1
    float* deg_inv = (float*)(row_start + N_NODES + 1);    // N_NODES
    int* bucket_count  = (int*)(deg_inv + N_NODES);        // NBUCK
    int* bucket_base   = bucket_count + 256;               // NBUCK+1
    int* bucket_cursor = bucket_base + 260;                // NBUCK
    int2* pairs = (int2*)bufA;  // 12.8 MB, dead before gemm1 writes bufA

    // CSR build (coalesced bucket sort)
    hipMemsetAsync(bucket_count, 0, NBUCK * sizeof(int), stream);
    bucket_hist_kernel<<<512, 256, 0, stream>>>(row, bucket_count);
    bucket_scan_kernel<<<1, 256, 0, stream>>>(bucket_count, bucket_base, bucket_cursor);
    bucketize_kernel<<<(N_EDGES + EPB - 1) / EPB, 256, 0, stream>>>(row, col, bucket_cursor, pairs);
    csr_finalize_kernel<<<NBUCK, 512, 0, stream>>>(pairs, bucket_base, csr_col, row_start, deg_inv);

    // layer 1
    gemm_bias_kernel<<<N_NODES / 32, 256, 0, stream>>>(x, W1, b1, bufA);
    spmm_kernel<true><<<(N_NODES * 64) / 256, 256, 0, stream>>>(bufA, row_start, csr_col, deg_inv, bufB);

    // layer 2
    gemm_bias_kernel<<<N_NODES / 32, 256, 0, stream>>>(bufB, W2, b2, bufA);
    spmm_kernel<false><<<(N_NODES * 64) / 256, 256, 0, stream>>>(bufA, row_start, csr_col, deg_inv, out);
}

// Round 4
// 349.847 us; speedup vs baseline: 2.4427x; 1.6722x over previous
//
#include <hip/hip_runtime.h>
#include <math.h>

#define N_NODES 100000
#define N_EDGES 1600000
#define F 128
#define NBUCK 196
#define EPB 8192
#define MAXB 10240

typedef short bf16x8 __attribute__((ext_vector_type(8)));
typedef float f32x4 __attribute__((ext_vector_type(4)));

__device__ inline ushort f2bf(float f) {  // RNE f32->bf16
    uint u = __float_as_uint(f);
    return (ushort)((u + 0x7FFFu + ((u >> 16) & 1u)) >> 16);
}

// ---------------- CSR build (unchanged from R3) ----------------

__global__ __launch_bounds__(256) void bucket_hist_kernel(const int* __restrict__ row,
                                                          int* __restrict__ bucket_count) {
    __shared__ int lc[NBUCK];
    for (int i = threadIdx.x; i < NBUCK; i += 256) lc[i] = 0;
    __syncthreads();
    const int stride = gridDim.x * 256;
    for (int e = blockIdx.x * 256 + threadIdx.x; e < N_EDGES; e += stride)
        atomicAdd(&lc[row[e] >> 9], 1);
    __syncthreads();
    for (int i = threadIdx.x; i < NBUCK; i += 256)
        if (lc[i]) atomicAdd(&bucket_count[i], lc[i]);
}

__global__ __launch_bounds__(256) void bucket_scan_kernel(const int* __restrict__ bucket_count,
                                                          int* __restrict__ bucket_base,
                                                          int* __restrict__ bucket_cursor) {
    __shared__ int s[256];
    const int tid = threadIdx.x;
    int v = (tid < NBUCK) ? bucket_count[tid] : 0;
    s[tid] = v;
    __syncthreads();
    for (int off = 1; off < 256; off <<= 1) {
        int t = (tid >= off) ? s[tid - off] : 0;
        __syncthreads();
        s[tid] += t;
        __syncthreads();
    }
    if (tid < NBUCK) {
        int ex = s[tid] - v;
        bucket_base[tid] = ex;
        bucket_cursor[tid] = ex;
    }
    if (tid == NBUCK - 1) bucket_base[NBUCK] = s[tid];
}

__global__ __launch_bounds__(256) void bucketize_kernel(const int* __restrict__ row,
                                                        const int* __restrict__ col,
                                                        int* __restrict__ bucket_cursor,
                                                        int2* __restrict__ pairs) {
    __shared__ int2 stage[EPB];
    __shared__ int tgt[EPB];
    __shared__ int lcnt[NBUCK], lcnt2[NBUCK], loff[NBUCK], gbase[NBUCK];
    __shared__ int s[256];
    const int tid = threadIdx.x;
    const int base = blockIdx.x * EPB;

    for (int i = tid; i < NBUCK; i += 256) { lcnt[i] = 0; lcnt2[i] = 0; }
    __syncthreads();
    for (int i = 0; i < 32; ++i) {
        int e = base + i * 256 + tid;
        if (e < N_EDGES) atomicAdd(&lcnt[row[e] >> 9], 1);
    }
    __syncthreads();
    {
        int v = (tid < NBUCK) ? lcnt[tid] : 0;
        s[tid] = v;
        __syncthreads();
        for (int off = 1; off < 256; off <<= 1) {
            int t = (tid >= off) ? s[tid - off] : 0;
            __syncthreads();
            s[tid] += t;
            __syncthreads();
        }
        if (tid < NBUCK) loff[tid] = s[tid] - v;
    }
    if (tid < NBUCK) {
        int c = lcnt[tid];
        gbase[tid] = c ? atomicAdd(&bucket_cursor[tid], c) : 0;
    }
    __syncthreads();
    for (int i = 0; i < 32; ++i) {
        int e = base + i * 256 + tid;
        if (e < N_EDGES) {
            int r = row[e], c = col[e];
            int b = r >> 9;
            int rk = atomicAdd(&lcnt2[b], 1);
            int q = loff[b] + rk;
            stage[q] = make_int2(r, c);
            tgt[q] = gbase[b] + rk;
        }
    }
    __syncthreads();
    const int cnt = min(N_EDGES - base, EPB);
    for (int q = tid; q < cnt; q += 256) pairs[tgt[q]] = stage[q];
}

__global__ __launch_bounds__(512) void csr_finalize_kernel(const int2* __restrict__ pairs,
                                                           const int* __restrict__ bucket_base,
                                                           int* __restrict__ csr_col,
                                                           int* __restrict__ row_start,
                                                           float* __restrict__ deg_inv) {
    __shared__ int rcnt[512], rcnt2[512], ssc[512], roff[512];
    __shared__ int colstage[MAXB];
    const int tid = threadIdx.x;
    const int b = blockIdx.x;
    const int s0 = bucket_base[b], e0 = bucket_base[b + 1];

    rcnt[tid] = 0;
    rcnt2[tid] = 0;
    __syncthreads();
    for (int q = s0 + tid; q < e0; q += 512) atomicAdd(&rcnt[pairs[q].x & 511], 1);
    __syncthreads();
    const int d = rcnt[tid];
    ssc[tid] = d;
    __syncthreads();
    for (int off = 1; off < 512; off <<= 1) {
        int t = (tid >= off) ? ssc[tid - off] : 0;
        __syncthreads();
        ssc[tid] += t;
        __syncthreads();
    }
    const int excl = ssc[tid] - d;
    roff[tid] = excl;
    const int grow = (b << 9) + tid;
    if (grow < N_NODES) {
        row_start[grow] = s0 + excl;
        deg_inv[grow] = d ? 1.0f / (float)d : 0.0f;
    } else if (grow == N_NODES) {
        row_start[N_NODES] = s0 + excl;
    }
    __syncthreads();
    for (int q = s0 + tid; q < e0; q += 512) {
        int2 pc = pairs[q];
        int lr = pc.x & 511;
        int rk = atomicAdd(&rcnt2[lr], 1);
        int idx = roff[lr] + rk;
        if (idx < MAXB) colstage[idx] = pc.y;
        else csr_col[s0 + idx] = pc.y;
    }
    __syncthreads();
    const int cap = min(e0 - s0, MAXB);
    for (int q = tid; q < cap; q += 512) csr_col[s0 + q] = colstage[q];
}

// ---------------- W -> bf16 conversion (tiny) ----------------

__global__ __launch_bounds__(256) void convert_w_kernel(const float* __restrict__ W1,
                                                        const float* __restrict__ W2,
                                                        ushort* __restrict__ W1b,
                                                        ushort* __restrict__ W2b) {
    int i = blockIdx.x * 256 + threadIdx.x;
    if (i < F * F) {
        W1b[i] = f2bf(W1[i]);
        W2b[i] = f2bf(W2[i]);
    }
}

// ---------------- MFMA GEMM: Y(bf16) = X @ W^T + b ----------------
// Block = 256 thr = 4 waves; each wave computes 16 rows x 128 cols.
// A-frag: A[m=lane&15][k=quad*8+j] from LDS xs (row pad 136 -> 2-way banks).
// B-frag: B[k=quad*8+j][n=lane&15] = W[n][k] -> 8 contiguous bf16 from global.
// C/D:    col=lane&15, row=quad*4+reg. Epilogue transposes via LDS (overlaid
// on xs after a barrier) for coalesced bf16 stores.

template <bool IN_BF16>
__global__ __launch_bounds__(256, 4) void gemm_mfma_kernel(const void* __restrict__ Xv,
                                                           const ushort* __restrict__ Wb,
                                                           const float* __restrict__ bias,
                                                           ushort* __restrict__ Y) {
    __shared__ __align__(16) char smraw[4 * 16 * 132 * 4];  // 33792 B (>= 64*136*2)
    ushort* xs = (ushort*)smraw;                     // [64][136] bf16
    float (*ys)[16][132] = (float(*)[16][132])smraw; // [4][16][132] f32

    const int tid = threadIdx.x;
    const int m0 = blockIdx.x << 6;

    if (!IN_BF16) {
        const float* X = (const float*)Xv;
        for (int i = 0; i < 8; ++i) {
            int f = i * 256 + tid;             // 2048 float4-chunks
            int r = f >> 5, c = f & 31;
            int gr = m0 + r; gr = gr < N_NODES ? gr : N_NODES - 1;
            float4 v = *(const float4*)&X[(size_t)gr * F + (c << 2)];
            ushort4 o = {f2bf(v.x), f2bf(v.y), f2bf(v.z), f2bf(v.w)};
            *(ushort4*)&xs[r * 136 + (c << 2)] = o;
        }
    } else {
        const ushort* X = (const ushort*)Xv;
        for (int i = 0; i < 4; ++i) {
            int f = i * 256 + tid;             // 1024 uint4-chunks
            int r = f >> 4, c = f & 15;
            int gr = m0 + r; gr = gr < N_NODES ? gr : N_NODES - 1;
            uint4 v = *(const uint4*)&X[(size_t)gr * F + (c << 3)];
            *(uint4*)&xs[r * 136 + (c << 3)] = v;
        }
    }
    __syncthreads();

    const int w = tid >> 6;
    const int lane = tid & 63;
    const int q = lane >> 4;
    const int t = lane & 15;

    bf16x8 afr[4];
#pragma unroll
    for (int kk = 0; kk < 4; ++kk)
        afr[kk] = *(const bf16x8*)&xs[(w * 16 + t) * 136 + kk * 32 + q * 8];

    f32x4 acc[8];
#pragma unroll
    for (int j = 0; j < 8; ++j) acc[j] = (f32x4){0.f, 0.f, 0.f, 0.f};

#pragma unroll
    for (int j = 0; j < 8; ++j) {
        const ushort* wrow = &Wb[(j * 16 + t) * F + q * 8];
#pragma unroll
        for (int kk = 0; kk < 4; ++kk) {
            bf16x8 bfr = *(const bf16x8*)&wrow[kk * 32];
            acc[j] = __builtin_amdgcn_mfma_f32_16x16x32_bf16(afr[kk], bfr, acc[j], 0, 0, 0);
        }
    }

    __syncthreads();  // all waves done reading xs; overlay with ys

#pragma unroll
    for (int j = 0; j < 8; ++j) {
        float bb = bias[j * 16 + t];
#pragma unroll
        for (int r = 0; r < 4; ++r) ys[w][q * 4 + r][j * 16 + t] = acc[j][r] + bb;
    }
    // wave-local ys: compiler inserts lgkmcnt waits; no cross-wave sharing

    for (int i = 0; i < 4; ++i) {
        int c = i * 64 + lane;                 // 256 ushort8-chunks of 16x128
        int row = c >> 4, seg = c & 15;
        int gr = m0 + w * 16 + row;
        if (gr < N_NODES) {
            const float* src = &ys[w][row][seg * 8];
            float4 a = *(const float4*)src;
            float4 b = *(const float4*)(src + 4);
            uint4 o;
            o.x = (uint)f2bf(a.x) | ((uint)f2bf(a.y) << 16);
            o.y = (uint)f2bf(a.z) | ((uint)f2bf(a.w) << 16);
            o.z = (uint)f2bf(b.x) | ((uint)f2bf(b.y) << 16);
            o.w = (uint)f2bf(b.z) | ((uint)f2bf(b.w) << 16);
            *(uint4*)&Y[(size_t)gr * F + seg * 8] = o;
        }
    }
}

// ---------------- SpMM (mean agg) on bf16 rows ----------------
// One wave per node; quarter-wave per edge, lane loads 16 B (8 bf16) of the
// 256 B row; 2x unroll -> 8 gathers in flight. f32 accumulate, shfl-reduce.

__device__ inline void acc8(float* a, uint4 v) {
    a[0] += __uint_as_float(v.x << 16);
    a[1] += __uint_as_float(v.x & 0xFFFF0000u);
    a[2] += __uint_as_float(v.y << 16);
    a[3] += __uint_as_float(v.y & 0xFFFF0000u);
    a[4] += __uint_as_float(v.z << 16);
    a[5] += __uint_as_float(v.z & 0xFFFF0000u);
    a[6] += __uint_as_float(v.w << 16);
    a[7] += __uint_as_float(v.w & 0xFFFF0000u);
}

template <bool ELU, bool OUT_BF16>
__global__ __launch_bounds__(256) void spmm_kernel(const ushort* __restrict__ H,
                                                   const int* __restrict__ row_start,
                                                   const int* __restrict__ csr_col,
                                                   const float* __restrict__ deg_inv,
                                                   void* __restrict__ out) {
    const int node = (blockIdx.x * 256 + threadIdx.x) >> 6;
    const int lane = threadIdx.x & 63;
    const int q = lane >> 4;
    const int fo = (lane & 15) << 3;   // ushort offset within row

    const int s = row_start[node];
    const int e = row_start[node + 1];

    float a[8] = {};
    int p = s + q;
    while (p + 4 < e) {
        int c0 = csr_col[p];
        int c1 = csr_col[p + 4];
        uint4 v0 = *(const uint4*)&H[(size_t)c0 * F + fo];
        uint4 v1 = *(const uint4*)&H[(size_t)c1 * F + fo];
        acc8(a, v0);
        acc8(a, v1);
        p += 8;
    }
    if (p < e) {
        int c = csr_col[p];
        uint4 v = *(const uint4*)&H[(size_t)c * F + fo];
        acc8(a, v);
    }

#pragma unroll
    for (int i = 0; i < 8; ++i) a[i] += __shfl_down(a[i], 32);
#pragma unroll
    for (int i = 0; i < 8; ++i) a[i] += __shfl_down(a[i], 16);

    if (q == 0) {
        float di = deg_inv[node];
#pragma unroll
        for (int i = 0; i < 8; ++i) {
            a[i] *= di;
            if (ELU) a[i] = (a[i] > 0.f) ? a[i] : expm1f(a[i]);
        }
        if (OUT_BF16) {
            uint4 o;
            o.x = (uint)f2bf(a[0]) | ((uint)f2bf(a[1]) << 16);
            o.y = (uint)f2bf(a[2]) | ((uint)f2bf(a[3]) << 16);
            o.z = (uint)f2bf(a[4]) | ((uint)f2bf(a[5]) << 16);
            o.w = (uint)f2bf(a[6]) | ((uint)f2bf(a[7]) << 16);
            *(uint4*)&((ushort*)out)[(size_t)node * F + fo] = o;
        } else {
            float* of = &((float*)out)[(size_t)node * F + fo];
            *(float4*)of = (float4){a[0], a[1], a[2], a[3]};
            *(float4*)(of + 4) = (float4){a[4], a[5], a[6], a[7]};
        }
    }
}

// ---------------- launch ----------------

extern "C" void kernel_launch(void* const* d_in, const int* in_sizes, int n_in,
                              void* d_out, int out_size, void* d_ws, size_t ws_size,
                              hipStream_t stream) {
    const float* x  = (const float*)d_in[0];
    const int*   ei = (const int*)d_in[1];
    const float* W1 = (const float*)d_in[2];
    const float* b1 = (const float*)d_in[3];
    const float* W2 = (const float*)d_in[4];
    const float* b2 = (const float*)d_in[5];
    float* out = (float*)d_out;

    const int* row = ei;
    const int* col = ei + N_EDGES;

    // workspace layout (all offsets 16B-aligned)
    ushort* bufA = (ushort*)d_ws;                            // N*F bf16 (25.6 MB)
    ushort* bufB = bufA + (size_t)N_NODES * F;               // N*F bf16
    int* csr_col = (int*)(bufB + (size_t)N_NODES * F);       // N_EDGES
    int* row_start = csr_col + N_EDGES;                      // N+4 (padded)
    float* deg_inv = (float*)(row_start + N_NODES + 4);      // N
    int* bucket_count  = (int*)(deg_inv + N_NODES);          // 256
    int* bucket_base   = bucket_count + 256;                 // 256
    int* bucket_cursor = bucket_base + 256;                  // 256
    ushort* W1b = (ushort*)(bucket_cursor + 256);            // 16384
    ushort* W2b = W1b + F * F;                               // 16384
    int2* pairs = (int2*)bufA;  // 12.8 MB overlay, dead before gemm1

    // CSR build
    hipMemsetAsync(bucket_count, 0, NBUCK * sizeof(int), stream);
    bucket_hist_kernel<<<512, 256, 0, stream>>>(row, bucket_count);
    bucket_scan_kernel<<<1, 256, 0, stream>>>(bucket_count, bucket_base, bucket_cursor);
    bucketize_kernel<<<(N_EDGES + EPB - 1) / EPB, 256, 0, stream>>>(row, col, bucket_cursor, pairs);
    csr_finalize_kernel<<<NBUCK, 512, 0, stream>>>(pairs, bucket_base, csr_col, row_start, deg_inv);

    convert_w_kernel<<<64, 256, 0, stream>>>(W1, W2, W1b, W2b);

    const int gemm_blocks = (N_NODES + 63) / 64;   // 1563
    // layer 1
    gemm_mfma_kernel<false><<<gemm_blocks, 256, 0, stream>>>(x, W1b, b1, bufA);
    spmm_kernel<true, true><<<(N_NODES * 64) / 256, 256, 0, stream>>>(bufA, row_start, csr_col, deg_inv, bufB);
    // layer 2
    gemm_mfma_kernel<true><<<gemm_blocks, 256, 0, stream>>>(bufB, W2b, b2, bufA);
    spmm_kernel<false, false><<<(N_NODES * 64) / 256, 256, 0, stream>>>(bufA, row_start, csr_col, deg_inv, out);
}

// Round 6
// 327.648 us; speedup vs baseline: 2.6082x; 1.0678x over previous
//
#include <hip/hip_runtime.h>
#include <math.h>

#define N_NODES 100000
#define N_EDGES 1600000
#define F 128
#define NBUCK 196        // buckets of 512 rows
#define EPB 4096         // edges per bucketize block
#define CAP 9216         // fixed bucket region capacity (avg 8192, +11 sigma)

typedef _Float16 f16x2 __attribute__((ext_vector_type(2)));
typedef _Float16 f16x8 __attribute__((ext_vector_type(8)));
typedef __fp16 fp16x2 __attribute__((ext_vector_type(2)));
typedef float f32x2 __attribute__((ext_vector_type(2)));
typedef float f32x4 __attribute__((ext_vector_type(4)));

__device__ inline uint pkrtz(float a, float b) {
    union { fp16x2 h; uint u; } c;
    c.h = __builtin_amdgcn_cvt_pkrtz(a, b);
    return c.u;
}
__device__ inline f16x2 as2(uint u) {
    union { uint u; f16x2 h; } c; c.u = u; return c.h;
}

// ---------------- CSR build: single-pass bucket sort, fixed regions ----------------

__global__ __launch_bounds__(256) void bucketize_kernel(const int* __restrict__ row,
                                                        const int* __restrict__ col,
                                                        int* __restrict__ bucket_cursor,
                                                        int* __restrict__ pairs) {
    __shared__ int stage[EPB];
    __shared__ unsigned char bid[EPB];
    __shared__ int lcnt[NBUCK], lcur[NBUCK], loff[NBUCK], gbase[NBUCK];
    __shared__ int s[256];
    const int tid = threadIdx.x;
    const int base = blockIdx.x * EPB;
    const int cnt = min(N_EDGES - base, EPB);

    for (int i = tid; i < NBUCK; i += 256) { lcnt[i] = 0; lcur[i] = 0; }
    __syncthreads();
    for (int i = 0; i < EPB / 256; ++i) {
        int e = base + i * 256 + tid;
        if (e < N_EDGES) atomicAdd(&lcnt[row[e] >> 9], 1);
    }
    __syncthreads();
    {   // exclusive scan lcnt -> loff
        int v = (tid < NBUCK) ? lcnt[tid] : 0;
        s[tid] = v;
        __syncthreads();
        for (int off = 1; off < 256; off <<= 1) {
            int t = (tid >= off) ? s[tid - off] : 0;
            __syncthreads();
            s[tid] += t;
            __syncthreads();
        }
        if (tid < NBUCK) loff[tid] = s[tid] - v;
    }
    if (tid < NBUCK) {
        int c = lcnt[tid];
        gbase[tid] = c ? atomicAdd(&bucket_cursor[tid], c) : 0;
    }
    __syncthreads();
    for (int i = 0; i < EPB / 256; ++i) {
        int e = base + i * 256 + tid;
        if (e < N_EDGES) {
            int r = row[e], c = col[e];
            int b = r >> 9;
            int rk = atomicAdd(&lcur[b], 1);
            int q = loff[b] + rk;
            stage[q] = ((r & 511) << 17) | c;   // 9b local row | 17b col
            bid[q] = (unsigned char)b;
        }
    }
    __syncthreads();
    for (int q = tid; q < cnt; q += 256) {
        int b = bid[q];
        int t = gbase[b] + (q - loff[b]);
        if (t < CAP) pairs[b * CAP + t] = stage[q];
    }
}

__global__ __launch_bounds__(256) void bucket_scan_kernel(const int* __restrict__ bucket_cursor,
                                                          int* __restrict__ bucket_base) {
    __shared__ int s[256];
    const int tid = threadIdx.x;
    int v = (tid < NBUCK) ? bucket_cursor[tid] : 0;
    s[tid] = v;
    __syncthreads();
    for (int off = 1; off < 256; off <<= 1) {
        int t = (tid >= off) ? s[tid - off] : 0;
        __syncthreads();
        s[tid] += t;
        __syncthreads();
    }
    if (tid < NBUCK) bucket_base[tid] = s[tid] - v;
}

__global__ __launch_bounds__(512) void csr_finalize_kernel(const int* __restrict__ pairs,
                                                           const int* __restrict__ bucket_cursor,
                                                           const int* __restrict__ bucket_base,
                                                           int* __restrict__ csr_col,
                                                           int* __restrict__ row_start,
                                                           float* __restrict__ deg_inv) {
    __shared__ int rcnt[512], rcnt2[512], ssc[512], roff[512];
    __shared__ int colstage[CAP];
    const int tid = threadIdx.x;
    const int b = blockIdx.x;
    const int cnt = min(bucket_cursor[b], CAP);
    const int s0 = bucket_base[b];
    const int* reg = &pairs[b * CAP];

    rcnt[tid] = 0;
    rcnt2[tid] = 0;
    __syncthreads();
    for (int q = tid; q < cnt; q += 512) atomicAdd(&rcnt[reg[q] >> 17], 1);
    __syncthreads();
    const int d = rcnt[tid];
    ssc[tid] = d;
    __syncthreads();
    for (int off = 1; off < 512; off <<= 1) {
        int t = (tid >= off) ? ssc[tid - off] : 0;
        __syncthreads();
        ssc[tid] += t;
        __syncthreads();
    }
    const int excl = ssc[tid] - d;
    roff[tid] = excl;
    const int grow = (b << 9) + tid;
    if (grow < N_NODES) {
        row_start[grow] = s0 + excl;
        deg_inv[grow] = d ? 1.0f / (float)d : 0.0f;
    } else if (grow == N_NODES) {
        row_start[N_NODES] = s0 + excl;
    }
    __syncthreads();
    for (int q = tid; q < cnt; q += 512) {
        int v = reg[q];
        int lr = v >> 17;
        int rk = atomicAdd(&rcnt2[lr], 1);
        colstage[roff[lr] + rk] = v & 0x1FFFF;
    }
    __syncthreads();
    for (int q = tid; q < cnt; q += 512) csr_col[s0 + q] = colstage[q];
}

// ---------------- W -> f16 conversion (tiny) ----------------

__global__ __launch_bounds__(256) void convert_w_kernel(const float* __restrict__ W1,
                                                        const float* __restrict__ W2,
                                                        uint* __restrict__ W1h,
                                                        uint* __restrict__ W2h) {
    int i = blockIdx.x * 256 + threadIdx.x;   // pair index
    if (i < F * F / 2) {
        float2 a = *(const float2*)&W1[i * 2];
        float2 b = *(const float2*)&W2[i * 2];
        W1h[i] = pkrtz(a.x, a.y);
        W2h[i] = pkrtz(b.x, b.y);
    }
}

// ---------------- MFMA GEMM: Y(f16) = X @ W^T + b ----------------
// Block = 256 thr = 4 waves; wave computes 16 rows x 128 cols via 16x16x32_f16.
// A-frag from LDS (row pitch 136 -> benign 2-way), B-frag from global W (f16,
// L1/L2 resident, contiguous 16 B per lane). Epilogue: bias add in f32, LDS
// transpose (overlaid), pkrtz pack, coalesced 16 B stores.

template <bool IN_F16>
__global__ __launch_bounds__(256, 4) void gemm_mfma_kernel(const void* __restrict__ Xv,
                                                           const ushort* __restrict__ Wh,
                                                           const float* __restrict__ bias,
                                                           ushort* __restrict__ Y) {
    __shared__ __align__(16) char smraw[4 * 16 * 132 * 4];  // 33792 B
    ushort* xs = (ushort*)smraw;                     // [64][136] f16
    float (*ys)[16][132] = (float(*)[16][132])smraw; // [4][16][132] f32

    const int tid = threadIdx.x;
    const int m0 = blockIdx.x << 6;

    if (!IN_F16) {
        const float* X = (const float*)Xv;
        for (int i = 0; i < 8; ++i) {
            int f = i * 256 + tid;             // 2048 float4-chunks
            int r = f >> 5, c = f & 31;
            int gr = m0 + r; gr = gr < N_NODES ? gr : N_NODES - 1;
            float4 v = *(const float4*)&X[(size_t)gr * F + (c << 2)];
            uint2 o = {pkrtz(v.x, v.y), pkrtz(v.z, v.w)};
            *(uint2*)&xs[r * 136 + (c << 2)] = o;
        }
    } else {
        const ushort* X = (const ushort*)Xv;
        for (int i = 0; i < 4; ++i) {
            int f = i * 256 + tid;             // 1024 uint4-chunks
            int r = f >> 4, c = f & 15;
            int gr = m0 + r; gr = gr < N_NODES ? gr : N_NODES - 1;
            uint4 v = *(const uint4*)&X[(size_t)gr * F + (c << 3)];
            *(uint4*)&xs[r * 136 + (c << 3)] = v;
        }
    }
    __syncthreads();

    const int w = tid >> 6;
    const int lane = tid & 63;
    const int q = lane >> 4;
    const int t = lane & 15;

    f16x8 afr[4];
#pragma unroll
    for (int kk = 0; kk < 4; ++kk)
        afr[kk] = *(const f16x8*)&xs[(w * 16 + t) * 136 + kk * 32 + q * 8];

    f32x4 acc[8];
#pragma unroll
    for (int j = 0; j < 8; ++j) acc[j] = (f32x4){0.f, 0.f, 0.f, 0.f};

#pragma unroll
    for (int j = 0; j < 8; ++j) {
        const ushort* wrow = &Wh[(j * 16 + t) * F + q * 8];
#pragma unroll
        for (int kk = 0; kk < 4; ++kk) {
            f16x8 bfr = *(const f16x8*)&wrow[kk * 32];
            acc[j] = __builtin_amdgcn_mfma_f32_16x16x32_f16(afr[kk], bfr, acc[j], 0, 0, 0);
        }
    }

    __syncthreads();  // done reading xs; overlay with ys

#pragma unroll
    for (int j = 0; j < 8; ++j) {
        float bb = bias[j * 16 + t];
#pragma unroll
        for (int r = 0; r < 4; ++r) ys[w][q * 4 + r][j * 16 + t] = acc[j][r] + bb;
    }

    for (int i = 0; i < 4; ++i) {
        int c = i * 64 + lane;                 // 256 chunks of 8 floats
        int row = c >> 4, seg = c & 15;
        int gr = m0 + w * 16 + row;
        if (gr < N_NODES) {
            const float* src = &ys[w][row][seg * 8];
            float4 a = *(const float4*)src;
            float4 b = *(const float4*)(src + 4);
            uint4 o = {pkrtz(a.x, a.y), pkrtz(a.z, a.w), pkrtz(b.x, b.y), pkrtz(b.z, b.w)};
            *(uint4*)&Y[(size_t)gr * F + seg * 8] = o;
        }
    }
}

// ---------------- SpMM (mean agg) on f16 rows ----------------
// 4 nodes per wave (16 nodes/block): quarter-wave (16 lanes x 16 B) covers one
// full 256 B row; each quarter owns its node -> no reduction. 4-edge f16 tree
// add (v_pk_add_f16) then one unpack + v_pk_add_f32 -> ~24 VALU / 4 edges.

template <bool ELU, bool OUT_F32>
__global__ __launch_bounds__(256) void spmm_kernel(const ushort* __restrict__ H,
                                                   const int* __restrict__ row_start,
                                                   const int* __restrict__ csr_col,
                                                   const float* __restrict__ deg_inv,
                                                   void* __restrict__ out) {
    const int node = blockIdx.x * 16 + (threadIdx.x >> 4);
    const int fo = (threadIdx.x & 15) << 3;   // ushort offset in row

    const int s = row_start[node];
    const int e = row_start[node + 1];

    f32x2 a[4];
#pragma unroll
    for (int i = 0; i < 4; ++i) a[i] = (f32x2){0.f, 0.f};

    int p = s;
    while (p + 3 < e) {   // 4-edge tree
        int c0 = csr_col[p], c1 = csr_col[p + 1], c2 = csr_col[p + 2], c3 = csr_col[p + 3];
        uint4 v0 = *(const uint4*)&H[(size_t)c0 * F + fo];
        uint4 v1 = *(const uint4*)&H[(size_t)c1 * F + fo];
        uint4 v2 = *(const uint4*)&H[(size_t)c2 * F + fo];
        uint4 v3 = *(const uint4*)&H[(size_t)c3 * F + fo];
        f16x2 h0 = (as2(v0.x) + as2(v1.x)) + (as2(v2.x) + as2(v3.x));
        f16x2 h1 = (as2(v0.y) + as2(v1.y)) + (as2(v2.y) + as2(v3.y));
        f16x2 h2 = (as2(v0.z) + as2(v1.z)) + (as2(v2.z) + as2(v3.z));
        f16x2 h3 = (as2(v0.w) + as2(v1.w)) + (as2(v2.w) + as2(v3.w));
        a[0] += (f32x2){(float)h0.x, (float)h0.y};
        a[1] += (f32x2){(float)h1.x, (float)h1.y};
        a[2] += (f32x2){(float)h2.x, (float)h2.y};
        a[3] += (f32x2){(float)h3.x, (float)h3.y};
        p += 4;
    }
    if (p + 1 < e) {      // 2-edge
        int c0 = csr_col[p], c1 = csr_col[p + 1];
        uint4 v0 = *(const uint4*)&H[(size_t)c0 * F + fo];
        uint4 v1 = *(const uint4*)&H[(size_t)c1 * F + fo];
        f16x2 h0 = as2(v0.x) + as2(v1.x);
        f16x2 h1 = as2(v0.y) + as2(v1.y);
        f16x2 h2 = as2(v0.z) + as2(v1.z);
        f16x2 h3 = as2(v0.w) + as2(v1.w);
        a[0] += (f32x2){(float)h0.x, (float)h0.y};
        a[1] += (f32x2){(float)h1.x, (float)h1.y};
        a[2] += (f32x2){(float)h2.x, (float)h2.y};
        a[3] += (f32x2){(float)h3.x, (float)h3.y};
        p += 2;
    }
    if (p < e) {          // 1-edge tail
        int c = csr_col[p];
        uint4 v = *(const uint4*)&H[(size_t)c * F + fo];
        f16x2 h0 = as2(v.x), h1 = as2(v.y), h2 = as2(v.z), h3 = as2(v.w);
        a[0] += (f32x2){(float)h0.x, (float)h0.y};
        a[1] += (f32x2){(float)h1.x, (float)h1.y};
        a[2] += (f32x2){(float)h2.x, (float)h2.y};
        a[3] += (f32x2){(float)h3.x, (float)h3.y};
    }

    const float di = deg_inv[node];
    float r[8];
#pragma unroll
    for (int i = 0; i < 4; ++i) { r[2 * i] = a[i].x * di; r[2 * i + 1] = a[i].y * di; }
    if (ELU) {
#pragma unroll
        for (int i = 0; i < 8; ++i) r[i] = (r[i] > 0.f) ? r[i] : expm1f(r[i]);
    }
    if (OUT_F32) {
        float* of = &((float*)out)[(size_t)node * F + fo];
        *(float4*)of = (float4){r[0], r[1], r[2], r[3]};
        *(float4*)(of + 4) = (float4){r[4], r[5], r[6], r[7]};
    } else {
        uint4 o = {pkrtz(r[0], r[1]), pkrtz(r[2], r[3]), pkrtz(r[4], r[5]), pkrtz(r[6], r[7])};
        *(uint4*)&((ushort*)out)[(size_t)node * F + fo] = o;
    }
}

// ---------------- launch ----------------

extern "C" void kernel_launch(void* const* d_in, const int* in_sizes, int n_in,
                              void* d_out, int out_size, void* d_ws, size_t ws_size,
                              hipStream_t stream) {
    const float* x  = (const float*)d_in[0];
    const int*   ei = (const int*)d_in[1];
    const float* W1 = (const float*)d_in[2];
    const float* b1 = (const float*)d_in[3];
    const float* W2 = (const float*)d_in[4];
    const float* b2 = (const float*)d_in[5];
    float* out = (float*)d_out;

    const int* row = ei;
    const int* col = ei + N_EDGES;

    // workspace layout (16B-aligned)
    ushort* bufA = (ushort*)d_ws;                            // N*F f16 (25.6 MB)
    ushort* bufB = bufA + (size_t)N_NODES * F;               // N*F f16
    int* csr_col = (int*)(bufB + (size_t)N_NODES * F);       // N_EDGES
    int* row_start = csr_col + N_EDGES;                      // N+4
    float* deg_inv = (float*)(row_start + N_NODES + 4);      // N
    int* bucket_cursor = (int*)(deg_inv + N_NODES);          // 256
    int* bucket_base   = bucket_cursor + 256;                // 256
    uint* W1h = (uint*)(bucket_base + 256);                  // 8192 uints
    uint* W2h = W1h + F * F / 2;                             // 8192 uints
    int* pairs = (int*)bufA;  // NBUCK*CAP ints = 7.2 MB overlay, dead before gemm1

    // CSR build
    (void)hipMemsetAsync(bucket_cursor, 0, NBUCK * sizeof(int), stream);
    bucketize_kernel<<<(N_EDGES + EPB - 1) / EPB, 256, 0, stream>>>(row, col, bucket_cursor, pairs);
    bucket_scan_kernel<<<1, 256, 0, stream>>>(bucket_cursor, bucket_base);
    csr_finalize_kernel<<<NBUCK, 512, 0, stream>>>(pairs, bucket_cursor, bucket_base,
                                                   csr_col, row_start, deg_inv);

    convert_w_kernel<<<32, 256, 0, stream>>>(W1, W2, W1h, W2h);

    const int gemm_blocks = (N_NODES + 63) / 64;   // 1563
    // layer 1
    gemm_mfma_kernel<false><<<gemm_blocks, 256, 0, stream>>>(x, (const ushort*)W1h, b1, bufA);
    spmm_kernel<true, false><<<N_NODES / 16, 256, 0, stream>>>(bufA, row_start, csr_col, deg_inv, bufB);
    // layer 2
    gemm_mfma_kernel<true><<<gemm_blocks, 256, 0, stream>>>(bufB, (const ushort*)W2h, b2, bufA);
    spmm_kernel<false, true><<<N_NODES / 16, 256, 0, stream>>>(bufA, row_start, csr_col, deg_inv, out);
}

// Round 7
// 318.479 us; speedup vs baseline: 2.6833x; 1.0288x over previous
//
#include <hip/hip_runtime.h>
#include <math.h>

#define N_NODES 100000
#define N_EDGES 1600000
#define F 128
#define NBUCK 196        // buckets of 512 rows
#define EPB 4096         // edges per bucketize block
#define CAP 9216         // fixed bucket region capacity (avg 8192, +11 sigma)

typedef _Float16 f16x2 __attribute__((ext_vector_type(2)));
typedef _Float16 f16x8 __attribute__((ext_vector_type(8)));
typedef __fp16 fp16x2 __attribute__((ext_vector_type(2)));
typedef float f32x2 __attribute__((ext_vector_type(2)));
typedef float f32x4 __attribute__((ext_vector_type(4)));

__device__ inline uint pkrtz(float a, float b) {
    union { fp16x2 h; uint u; } c;
    c.h = __builtin_amdgcn_cvt_pkrtz(a, b);
    return c.u;
}
__device__ inline f16x2 as2(uint u) {
    union { uint u; f16x2 h; } c; c.u = u; return c.h;
}

__device__ inline int wave_incl_scan(int v, int lane) {
#pragma unroll
    for (int off = 1; off < 64; off <<= 1) {
        int t = __shfl_up(v, off);
        if (lane >= off) v += t;
    }
    return v;
}

// ---------------- CSR build: single-pass bucket sort, fixed regions ----------------
// R6 post-mortem: barrier-ladder scans + 0.77 blocks/CU made the build the
// hidden ~140us. Wave-scans (2 barriers instead of 18) + fixed csr_col
// regions (no cross-bucket scan, one fewer kernel) + int2{start,deg} rows.

__global__ __launch_bounds__(256) void bucketize_kernel(const int* __restrict__ row,
                                                        const int* __restrict__ col,
                                                        int* __restrict__ bucket_cursor,
                                                        int* __restrict__ pairs) {
    __shared__ int stage[EPB];
    __shared__ unsigned char bid[EPB];
    __shared__ int lcnt[NBUCK], lcur[NBUCK], loff[NBUCK], gbase[NBUCK];
    __shared__ int wsum[4];
    const int tid = threadIdx.x;
    const int lane = tid & 63;
    const int wid = tid >> 6;
    const int base = blockIdx.x * EPB;
    const int cnt = min(N_EDGES - base, EPB);

    for (int i = tid; i < NBUCK; i += 256) { lcnt[i] = 0; lcur[i] = 0; }
    __syncthreads();
    for (int i = 0; i < EPB / 256; ++i) {
        int e = base + i * 256 + tid;
        if (e < N_EDGES) atomicAdd(&lcnt[row[e] >> 9], 1);
    }
    __syncthreads();
    {   // exclusive scan of lcnt -> loff (wave scan + 4-wave combine)
        int v = (tid < NBUCK) ? lcnt[tid] : 0;
        int inc = wave_incl_scan(v, lane);
        if (lane == 63) wsum[wid] = inc;
        __syncthreads();
        if (tid == 0) {
            int a = 0;
#pragma unroll
            for (int i = 0; i < 4; ++i) { int t = wsum[i]; wsum[i] = a; a += t; }
        }
        __syncthreads();
        if (tid < NBUCK) loff[tid] = inc - v + wsum[wid];
    }
    if (tid < NBUCK) {
        int c = lcnt[tid];
        gbase[tid] = c ? atomicAdd(&bucket_cursor[tid], c) : 0;
    }
    __syncthreads();
    for (int i = 0; i < EPB / 256; ++i) {
        int e = base + i * 256 + tid;
        if (e < N_EDGES) {
            int r = row[e], c = col[e];
            int b = r >> 9;
            int rk = atomicAdd(&lcur[b], 1);
            int q = loff[b] + rk;
            stage[q] = ((r & 511) << 17) | c;   // 9b local row | 17b col
            bid[q] = (unsigned char)b;
        }
    }
    __syncthreads();
    for (int q = tid; q < cnt; q += 256) {
        int b = bid[q];
        int t = gbase[b] + (q - loff[b]);
        if (t < CAP) pairs[b * CAP + t] = stage[q];
    }
}

__global__ __launch_bounds__(512) void csr_finalize_kernel(const int* __restrict__ pairs,
                                                           const int* __restrict__ bucket_cursor,
                                                           int* __restrict__ csr_col,
                                                           int2* __restrict__ rs,
                                                           float* __restrict__ deg_inv) {
    __shared__ int rcnt[512], rcnt2[512], roff[512];
    __shared__ int colstage[CAP];
    __shared__ int wsum[8];
    const int tid = threadIdx.x;
    const int lane = tid & 63;
    const int wid = tid >> 6;
    const int b = blockIdx.x;
    const int cnt = min(bucket_cursor[b], CAP);
    const int base = b * CAP;
    const int* reg = &pairs[base];

    rcnt[tid] = 0;
    rcnt2[tid] = 0;
    __syncthreads();
    for (int q = tid; q < cnt; q += 512) atomicAdd(&rcnt[reg[q] >> 17], 1);
    __syncthreads();
    const int d = rcnt[tid];
    // exclusive scan of rcnt -> roff (wave scan + 8-wave combine)
    int inc = wave_incl_scan(d, lane);
    if (lane == 63) wsum[wid] = inc;
    __syncthreads();
    if (tid == 0) {
        int a = 0;
#pragma unroll
        for (int i = 0; i < 8; ++i) { int t = wsum[i]; wsum[i] = a; a += t; }
    }
    __syncthreads();
    const int excl = inc - d + wsum[wid];
    roff[tid] = excl;
    const int grow = (b << 9) + tid;
    if (grow < N_NODES) {
        rs[grow] = make_int2(base + excl, d);
        deg_inv[grow] = d ? 1.0f / (float)d : 0.0f;
    }
    __syncthreads();
    for (int q = tid; q < cnt; q += 512) {
        int v = reg[q];
        int lr = v >> 17;
        int rk = atomicAdd(&rcnt2[lr], 1);
        colstage[roff[lr] + rk] = v & 0x1FFFF;
    }
    __syncthreads();
    for (int q = tid; q < cnt; q += 512) csr_col[base + q] = colstage[q];
}

// ---------------- W -> f16 conversion (tiny) ----------------

__global__ __launch_bounds__(256) void convert_w_kernel(const float* __restrict__ W1,
                                                        const float* __restrict__ W2,
                                                        uint* __restrict__ W1h,
                                                        uint* __restrict__ W2h) {
    int i = blockIdx.x * 256 + threadIdx.x;   // pair index
    if (i < F * F / 2) {
        float2 a = *(const float2*)&W1[i * 2];
        float2 b = *(const float2*)&W2[i * 2];
        W1h[i] = pkrtz(a.x, a.y);
        W2h[i] = pkrtz(b.x, b.y);
    }
}

// ---------------- MFMA GEMM: Y(f16) = X @ W^T + b ----------------
// Block = 256 thr = 4 waves; wave computes 16 rows x 128 cols via 16x16x32_f16.
// A-frag from LDS (row pitch 136 -> benign 2-way), B-frag from global W (f16,
// L1-resident, contiguous 16 B per lane). Epilogue: bias add in f32, LDS
// transpose (overlaid), pkrtz pack, coalesced 16 B stores.

template <bool IN_F16>
__global__ __launch_bounds__(256, 4) void gemm_mfma_kernel(const void* __restrict__ Xv,
                                                           const ushort* __restrict__ Wh,
                                                           const float* __restrict__ bias,
                                                           ushort* __restrict__ Y) {
    __shared__ __align__(16) char smraw[4 * 16 * 132 * 4];  // 33792 B
    ushort* xs = (ushort*)smraw;                     // [64][136] f16
    float (*ys)[16][132] = (float(*)[16][132])smraw; // [4][16][132] f32

    const int tid = threadIdx.x;
    const int m0 = blockIdx.x << 6;

    if (!IN_F16) {
        const float* X = (const float*)Xv;
        for (int i = 0; i < 8; ++i) {
            int f = i * 256 + tid;             // 2048 float4-chunks
            int r = f >> 5, c = f & 31;
            int gr = m0 + r; gr = gr < N_NODES ? gr : N_NODES - 1;
            float4 v = *(const float4*)&X[(size_t)gr * F + (c << 2)];
            uint2 o = {pkrtz(v.x, v.y), pkrtz(v.z, v.w)};
            *(uint2*)&xs[r * 136 + (c << 2)] = o;
        }
    } else {
        const ushort* X = (const ushort*)Xv;
        for (int i = 0; i < 4; ++i) {
            int f = i * 256 + tid;             // 1024 uint4-chunks
            int r = f >> 4, c = f & 15;
            int gr = m0 + r; gr = gr < N_NODES ? gr : N_NODES - 1;
            uint4 v = *(const uint4*)&X[(size_t)gr * F + (c << 3)];
            *(uint4*)&xs[r * 136 + (c << 3)] = v;
        }
    }
    __syncthreads();

    const int w = tid >> 6;
    const int lane = tid & 63;
    const int q = lane >> 4;
    const int t = lane & 15;

    f16x8 afr[4];
#pragma unroll
    for (int kk = 0; kk < 4; ++kk)
        afr[kk] = *(const f16x8*)&xs[(w * 16 + t) * 136 + kk * 32 + q * 8];

    f32x4 acc[8];
#pragma unroll
    for (int j = 0; j < 8; ++j) acc[j] = (f32x4){0.f, 0.f, 0.f, 0.f};

#pragma unroll
    for (int j = 0; j < 8; ++j) {
        const ushort* wrow = &Wh[(j * 16 + t) * F + q * 8];
#pragma unroll
        for (int kk = 0; kk < 4; ++kk) {
            f16x8 bfr = *(const f16x8*)&wrow[kk * 32];
            acc[j] = __builtin_amdgcn_mfma_f32_16x16x32_f16(afr[kk], bfr, acc[j], 0, 0, 0);
        }
    }

    __syncthreads();  // done reading xs; overlay with ys

#pragma unroll
    for (int j = 0; j < 8; ++j) {
        float bb = bias[j * 16 + t];
#pragma unroll
        for (int r = 0; r < 4; ++r) ys[w][q * 4 + r][j * 16 + t] = acc[j][r] + bb;
    }

    for (int i = 0; i < 4; ++i) {
        int c = i * 64 + lane;                 // 256 chunks of 8 floats
        int row = c >> 4, seg = c & 15;
        int gr = m0 + w * 16 + row;
        if (gr < N_NODES) {
            const float* src = &ys[w][row][seg * 8];
            float4 a = *(const float4*)src;
            float4 b = *(const float4*)(src + 4);
            uint4 o = {pkrtz(a.x, a.y), pkrtz(a.z, a.w), pkrtz(b.x, b.y), pkrtz(b.z, b.w)};
            *(uint4*)&Y[(size_t)gr * F + seg * 8] = o;
        }
    }
}

// ---------------- SpMM (mean agg) on f16 rows ----------------
// 4 nodes per wave (16 nodes/block): quarter-wave (16 lanes x 16 B) covers one
// full 256 B row; each quarter owns its node -> no reduction. 4-edge f16 tree
// add (v_pk_add_f16) then one unpack + v_pk_add_f32.

template <bool ELU, bool OUT_F32>
__global__ __launch_bounds__(256) void spmm_kernel(const ushort* __restrict__ H,
                                                   const int2* __restrict__ rs,
                                                   const int* __restrict__ csr_col,
                                                   const float* __restrict__ deg_inv,
                                                   void* __restrict__ out) {
    const int node = blockIdx.x * 16 + (threadIdx.x >> 4);
    const int fo = (threadIdx.x & 15) << 3;   // ushort offset in row

    const int2 sd = rs[node];
    const int s = sd.x;
    const int e = s + sd.y;

    f32x2 a[4];
#pragma unroll
    for (int i = 0; i < 4; ++i) a[i] = (f32x2){0.f, 0.f};

    int p = s;
    while (p + 3 < e) {   // 4-edge tree
        int c0 = csr_col[p], c1 = csr_col[p + 1], c2 = csr_col[p + 2], c3 = csr_col[p + 3];
        uint4 v0 = *(const uint4*)&H[(size_t)c0 * F + fo];
        uint4 v1 = *(const uint4*)&H[(size_t)c1 * F + fo];
        uint4 v2 = *(const uint4*)&H[(size_t)c2 * F + fo];
        uint4 v3 = *(const uint4*)&H[(size_t)c3 * F + fo];
        f16x2 h0 = (as2(v0.x) + as2(v1.x)) + (as2(v2.x) + as2(v3.x));
        f16x2 h1 = (as2(v0.y) + as2(v1.y)) + (as2(v2.y) + as2(v3.y));
        f16x2 h2 = (as2(v0.z) + as2(v1.z)) + (as2(v2.z) + as2(v3.z));
        f16x2 h3 = (as2(v0.w) + as2(v1.w)) + (as2(v2.w) + as2(v3.w));
        a[0] += (f32x2){(float)h0.x, (float)h0.y};
        a[1] += (f32x2){(float)h1.x, (float)h1.y};
        a[2] += (f32x2){(float)h2.x, (float)h2.y};
        a[3] += (f32x2){(float)h3.x, (float)h3.y};
        p += 4;
    }
    if (p + 1 < e) {      // 2-edge
        int c0 = csr_col[p], c1 = csr_col[p + 1];
        uint4 v0 = *(const uint4*)&H[(size_t)c0 * F + fo];
        uint4 v1 = *(const uint4*)&H[(size_t)c1 * F + fo];
        f16x2 h0 = as2(v0.x) + as2(v1.x);
        f16x2 h1 = as2(v0.y) + as2(v1.y);
        f16x2 h2 = as2(v0.z) + as2(v1.z);
        f16x2 h3 = as2(v0.w) + as2(v1.w);
        a[0] += (f32x2){(float)h0.x, (float)h0.y};
        a[1] += (f32x2){(float)h1.x, (float)h1.y};
        a[2] += (f32x2){(float)h2.x, (float)h2.y};
        a[3] += (f32x2){(float)h3.x, (float)h3.y};
        p += 2;
    }
    if (p < e) {          // 1-edge tail
        int c = csr_col[p];
        uint4 v = *(const uint4*)&H[(size_t)c * F + fo];
        f16x2 h0 = as2(v.x), h1 = as2(v.y), h2 = as2(v.z), h3 = as2(v.w);
        a[0] += (f32x2){(float)h0.x, (float)h0.y};
        a[1] += (f32x2){(float)h1.x, (float)h1.y};
        a[2] += (f32x2){(float)h2.x, (float)h2.y};
        a[3] += (f32x2){(float)h3.x, (float)h3.y};
    }

    const float di = deg_inv[node];
    float r[8];
#pragma unroll
    for (int i = 0; i < 4; ++i) { r[2 * i] = a[i].x * di; r[2 * i + 1] = a[i].y * di; }
    if (ELU) {
#pragma unroll
        for (int i = 0; i < 8; ++i) r[i] = (r[i] > 0.f) ? r[i] : expm1f(r[i]);
    }
    if (OUT_F32) {
        float* of = &((float*)out)[(size_t)node * F + fo];
        *(float4*)of = (float4){r[0], r[1], r[2], r[3]};
        *(float4*)(of + 4) = (float4){r[4], r[5], r[6], r[7]};
    } else {
        uint4 o = {pkrtz(r[0], r[1]), pkrtz(r[2], r[3]), pkrtz(r[4], r[5]), pkrtz(r[6], r[7])};
        *(uint4*)&((ushort*)out)[(size_t)node * F + fo] = o;
    }
}

// ---------------- launch ----------------

extern "C" void kernel_launch(void* const* d_in, const int* in_sizes, int n_in,
                              void* d_out, int out_size, void* d_ws, size_t ws_size,
                              hipStream_t stream) {
    const float* x  = (const float*)d_in[0];
    const int*   ei = (const int*)d_in[1];
    const float* W1 = (const float*)d_in[2];
    const float* b1 = (const float*)d_in[3];
    const float* W2 = (const float*)d_in[4];
    const float* b2 = (const float*)d_in[5];
    float* out = (float*)d_out;

    const int* row = ei;
    const int* col = ei + N_EDGES;

    // workspace layout (16B-aligned)
    ushort* bufA = (ushort*)d_ws;                            // N*F f16 (25.6 MB)
    ushort* bufB = bufA + (size_t)N_NODES * F;               // N*F f16
    int* csr_col = (int*)(bufB + (size_t)N_NODES * F);       // NBUCK*CAP (7.2 MB)
    int2* rs = (int2*)(csr_col + NBUCK * CAP);               // N {start,deg}
    float* deg_inv = (float*)(rs + N_NODES + 4);             // N
    int* bucket_cursor = (int*)(deg_inv + N_NODES);          // 256
    uint* W1h = (uint*)(bucket_cursor + 256);                // 8192 uints
    uint* W2h = W1h + F * F / 2;                             // 8192 uints
    int* pairs = (int*)bufA;  // NBUCK*CAP ints = 7.2 MB overlay, dead before gemm1

    // CSR build
    (void)hipMemsetAsync(bucket_cursor, 0, NBUCK * sizeof(int), stream);
    bucketize_kernel<<<(N_EDGES + EPB - 1) / EPB, 256, 0, stream>>>(row, col, bucket_cursor, pairs);
    csr_finalize_kernel<<<NBUCK, 512, 0, stream>>>(pairs, bucket_cursor, csr_col, rs, deg_inv);

    convert_w_kernel<<<32, 256, 0, stream>>>(W1, W2, W1h, W2h);

    const int gemm_blocks = (N_NODES + 63) / 64;   // 1563
    // layer 1
    gemm_mfma_kernel<false><<<gemm_blocks, 256, 0, stream>>>(x, (const ushort*)W1h, b1, bufA);
    spmm_kernel<true, false><<<N_NODES / 16, 256, 0, stream>>>(bufA, rs, csr_col, deg_inv, bufB);
    // layer 2
    gemm_mfma_kernel<true><<<gemm_blocks, 256, 0, stream>>>(bufB, (const ushort*)W2h, b2, bufA);
    spmm_kernel<false, true><<<N_NODES / 16, 256, 0, stream>>>(bufA, rs, csr_col, deg_inv, out);
}